// Round 1
// baseline (529.890 us; speedup 1.0000x reference)
//
#include <hip/hip_runtime.h>
#include <hip/hip_bf16.h>
#include <stdint.h>

// ---------------- common types / helpers ----------------

typedef __bf16 bf16x8 __attribute__((ext_vector_type(8)));
typedef float  f32x4  __attribute__((ext_vector_type(4)));
typedef short  s16x8  __attribute__((ext_vector_type(8)));

__device__ __forceinline__ f32x4 mfma_bf16(s16x8 a, s16x8 b, f32x4 c) {
  return __builtin_amdgcn_mfma_f32_16x16x32_bf16(
      __builtin_bit_cast(bf16x8, a), __builtin_bit_cast(bf16x8, b), c, 0, 0, 0);
}

__device__ __forceinline__ unsigned short f2bf(float f) {
  unsigned u = __float_as_uint(f);
  u = u + 0x7FFFu + ((u >> 16) & 1u);   // RNE
  return (unsigned short)(u >> 16);
}

__device__ __forceinline__ void load_lds16(const void* g, void* l) {
  __builtin_amdgcn_global_load_lds(
      (const __attribute__((address_space(1))) void*)g,
      (__attribute__((address_space(3))) void*)l, 16, 0, 0);
}

// ---------------- cast fp32 -> bf16 ----------------

__global__ void cast_kernel(const float* __restrict__ in,
                            unsigned short* __restrict__ out, int n4) {
  int i = blockIdx.x * blockDim.x + threadIdx.x;
  int stride = gridDim.x * blockDim.x;
  for (; i < n4; i += stride) {
    float4 v = reinterpret_cast<const float4*>(in)[i];
    ushort4 o;
    o.x = f2bf(v.x); o.y = f2bf(v.y); o.z = f2bf(v.z); o.w = f2bf(v.w);
    reinterpret_cast<ushort4*>(out)[i] = o;
  }
}

// ---------------- GEMM: C[M,N] = A[M,K] * B[N,K]^T (both bf16, K-major) ----------------
// 128x128 tile, BK=32, 4 waves 2x2 (each 64x64), 16x16x32 bf16 MFMA.
// LDS tiles [128][32] bf16, 16B-slot XOR swizzle: slot ^= row&3.
// Staged via global_load_lds (linear dest, pre-swizzled global source).

template <bool OUT_BF16>
__global__ __launch_bounds__(256)
void gemm_bt(const short* __restrict__ A, const short* __restrict__ Bw,
             void* __restrict__ Cp, int M, int N, int K) {
  __shared__ __align__(16) short lds_a[4096];
  __shared__ __align__(16) short lds_b[4096];

  const int nbn = N >> 7;
  const int mb  = blockIdx.x / nbn;
  const int nb  = blockIdx.x % nbn;
  const int tid = threadIdx.x;
  const int w   = tid >> 6, l = tid & 63;
  const int lg  = l >> 4, ll = l & 15;
  const int wm  = w >> 1, wn = w & 1;

  f32x4 acc[4][4];
#pragma unroll
  for (int i = 0; i < 4; ++i)
#pragma unroll
    for (int j = 0; j < 4; ++j) acc[i][j] = {0.f, 0.f, 0.f, 0.f};

  const int KT = K >> 5;
  for (int kt = 0; kt < KT; ++kt) {
    // stage: 16 chunks of 1KB (8 for A, 8 for B); wave w -> chunks 4w..4w+3
#pragma unroll
    for (int cc = 0; cc < 4; ++cc) {
      int chunk = w * 4 + cc;
      int c8    = chunk & 7;
      int row   = c8 * 16 + (l >> 2);      // tile row this lane fills
      int sg    = (l & 3) ^ (row & 3);     // pre-swizzled source 16B-slot
      if (chunk < 8) {
        const short* src = A + (size_t)(mb * 128 + row) * K + kt * 32 + sg * 8;
        load_lds16(src, lds_a + c8 * 512);
      } else {
        const short* src = Bw + (size_t)(nb * 128 + row) * K + kt * 32 + sg * 8;
        load_lds16(src, lds_b + c8 * 512);
      }
    }
    __syncthreads();

    s16x8 af[4], bf[4];
#pragma unroll
    for (int mi = 0; mi < 4; ++mi) {
      int row  = wm * 64 + mi * 16 + ll;
      int slot = lg ^ (row & 3);
      af[mi] = *reinterpret_cast<const s16x8*>(lds_a + row * 32 + slot * 8);
    }
#pragma unroll
    for (int nj = 0; nj < 4; ++nj) {
      int row  = wn * 64 + nj * 16 + ll;
      int slot = lg ^ (row & 3);
      bf[nj] = *reinterpret_cast<const s16x8*>(lds_b + row * 32 + slot * 8);
    }
#pragma unroll
    for (int mi = 0; mi < 4; ++mi)
#pragma unroll
      for (int nj = 0; nj < 4; ++nj)
        acc[mi][nj] = mfma_bf16(af[mi], bf[nj], acc[mi][nj]);
    __syncthreads();
  }

  // epilogue: C/D layout col = lane&15, row = (lane>>4)*4 + reg
#pragma unroll
  for (int mi = 0; mi < 4; ++mi) {
#pragma unroll
    for (int i = 0; i < 4; ++i) {
      size_t row = (size_t)(mb * 128 + wm * 64 + mi * 16 + lg * 4 + i);
#pragma unroll
      for (int nj = 0; nj < 4; ++nj) {
        int col = nb * 128 + wn * 64 + nj * 16 + ll;
        if (OUT_BF16)
          ((unsigned short*)Cp)[row * N + col] = f2bf(acc[mi][nj][i]);
        else
          ((float*)Cp)[row * N + col] = acc[mi][nj][i];
      }
    }
  }
}

// ---------------- flash attention ----------------
// grid = 32 (b,h) * 32 q-blocks of 64 rows; 256 threads = 4 waves, each wave
// owns 16 q rows. K/V tiles of 64 rows staged per iteration.
// qkv layout: [B*N, 3072], q at o = h*128+d, k at 1024+h*128+d, v at 2048+h*128+d.

__global__ __launch_bounds__(256)
void attn_fwd(const short* __restrict__ qkv, unsigned short* __restrict__ aout) {
  __shared__ __align__(16) short k_lds[64 * 128];   // [krow][d], swizzled (16KB)
  __shared__ __align__(16) short v_lds[128 * 64];   // V^T: [d][krow], swizzled (16KB)
  __shared__ __align__(16) short p_lds[4 * 16 * 64]; // per-wave P (8KB)

  const int bh = blockIdx.x >> 5;
  const int qb = blockIdx.x & 31;
  const int b = bh >> 3, h = bh & 7;
  const int tid = threadIdx.x;
  const int w = tid >> 6, l = tid & 63;
  const int lg = l >> 4, ll = l & 15;

  const size_t base = (size_t)b * 2048 * 3072 + (size_t)h * 128;

  // Q fragments in registers: A[i][kc]: i = ll (q row), kc = s*32 + lg*8 + b
  s16x8 aq[4];
  {
    const short* qrow = qkv + base + (size_t)(qb * 64 + w * 16 + ll) * 3072 + lg * 8;
#pragma unroll
    for (int s = 0; s < 4; ++s) aq[s] = *reinterpret_cast<const s16x8*>(qrow + s * 32);
  }

  f32x4 o[8];
#pragma unroll
  for (int n = 0; n < 8; ++n) o[n] = {0.f, 0.f, 0.f, 0.f};
  float M[4] = {-1e30f, -1e30f, -1e30f, -1e30f};
  float L[4] = {0.f, 0.f, 0.f, 0.f};
  const float scale = 0.08838834764831845f;  // 1/sqrt(128)
  const float LOG2E = 1.4426950408889634f;

  for (int kb = 0; kb < 32; ++kb) {
    // ---- stage K (global_load_lds, pre-swizzled source; rows 256B = 16 slots, xor row&7)
#pragma unroll
    for (int cc = 0; cc < 4; ++cc) {
      int c   = w * 4 + cc;          // chunk 0..15, 4 rows each
      int row = c * 4 + lg;
      int sd  = ll ^ (row & 7);
      const short* g = qkv + base + 1024 + (size_t)(kb * 64 + row) * 3072 + sd * 8;
      load_lds16(g, k_lds + c * 512);
    }
    // ---- stage V transposed (reg-staged): thread handles rows r0,r0+1, cols c0..c0+15
    {
      const int r0 = (tid & 31) * 2, c0 = (tid >> 5) * 16;
      const short* g = qkv + base + 2048 + (size_t)(kb * 64 + r0) * 3072 + c0;
      s16x8 v0a = *reinterpret_cast<const s16x8*>(g);
      s16x8 v0b = *reinterpret_cast<const s16x8*>(g + 8);
      s16x8 v1a = *reinterpret_cast<const s16x8*>(g + 3072);
      s16x8 v1b = *reinterpret_cast<const s16x8*>(g + 3072 + 8);
#pragma unroll
      for (int j = 0; j < 16; ++j) {
        int d = c0 + j;
        unsigned short e0 = (unsigned short)(j < 8 ? v0a[j] : v0b[j - 8]);
        unsigned short e1 = (unsigned short)(j < 8 ? v1a[j] : v1b[j - 8]);
        int byte = d * 128 + ((((r0 * 2) >> 4) ^ (d & 7)) << 4) + ((r0 * 2) & 15);
        *reinterpret_cast<unsigned int*>(reinterpret_cast<char*>(v_lds) + byte) =
            (unsigned int)e0 | ((unsigned int)e1 << 16);
      }
    }
    __syncthreads();

    // ---- S = Q K^T (own 16 q rows x 64 k cols)
    f32x4 sf[4];
#pragma unroll
    for (int j = 0; j < 4; ++j) sf[j] = {0.f, 0.f, 0.f, 0.f};
#pragma unroll
    for (int s = 0; s < 4; ++s) {
#pragma unroll
      for (int j = 0; j < 4; ++j) {
        int krow = j * 16 + ll;
        int slot = (s * 4 + lg) ^ (krow & 7);
        s16x8 bk = *reinterpret_cast<const s16x8*>(
            reinterpret_cast<const char*>(k_lds) + krow * 256 + (slot << 4));
        sf[j] = mfma_bf16(aq[s], bk, sf[j]);
      }
    }

    // ---- online softmax (rows live in 16-lane groups)
    float f[4];
#pragma unroll
    for (int i = 0; i < 4; ++i) {
#pragma unroll
      for (int j = 0; j < 4; ++j) sf[j][i] *= scale;
      float m = fmaxf(fmaxf(sf[0][i], sf[1][i]), fmaxf(sf[2][i], sf[3][i]));
#pragma unroll
      for (int d = 1; d < 16; d <<= 1) m = fmaxf(m, __shfl_xor(m, d));
      float Mn = fmaxf(M[i], m);
      f[i] = exp2f((M[i] - Mn) * LOG2E);
      M[i] = Mn;
      float rs = 0.f;
#pragma unroll
      for (int j = 0; j < 4; ++j) {
        float p = exp2f((sf[j][i] - Mn) * LOG2E);
        sf[j][i] = p;
        rs += p;
      }
#pragma unroll
      for (int d = 1; d < 16; d <<= 1) rs += __shfl_xor(rs, d);
      L[i] = L[i] * f[i] + rs;
    }
#pragma unroll
    for (int n = 0; n < 8; ++n)
#pragma unroll
      for (int i = 0; i < 4; ++i) o[n][i] *= f[i];

    // ---- P -> per-wave LDS (bf16, swizzled rows of 128B)
    short* pw = p_lds + w * 1024;
#pragma unroll
    for (int j = 0; j < 4; ++j) {
#pragma unroll
      for (int i = 0; i < 4; ++i) {
        int row = lg * 4 + i;
        int colbyte = (j * 16 + ll) * 2;
        int byte = row * 128 + (((colbyte >> 4) ^ (row & 7)) << 4) + (colbyte & 15);
        *reinterpret_cast<unsigned short*>(reinterpret_cast<char*>(pw) + byte) =
            f2bf(sf[j][i]);
      }
    }

    // ---- O += P V
#pragma unroll
    for (int kk = 0; kk < 2; ++kk) {
      int slot_a = (kk * 4 + lg) ^ (ll & 7);
      s16x8 ap = *reinterpret_cast<const s16x8*>(
          reinterpret_cast<const char*>(pw) + ll * 128 + (slot_a << 4));
#pragma unroll
      for (int n = 0; n < 8; ++n) {
        int d = n * 16 + ll;
        int slot_b = (kk * 4 + lg) ^ (d & 7);
        s16x8 bv = *reinterpret_cast<const s16x8*>(
            reinterpret_cast<const char*>(v_lds) + d * 128 + (slot_b << 4));
        o[n] = mfma_bf16(ap, bv, o[n]);
      }
    }
    __syncthreads();
  }

  // ---- epilogue: normalize and store bf16 [B*N, 1024]
  float inv[4];
#pragma unroll
  for (int i = 0; i < 4; ++i) inv[i] = 1.f / L[i];
#pragma unroll
  for (int n = 0; n < 8; ++n) {
#pragma unroll
    for (int i = 0; i < 4; ++i) {
      size_t row = (size_t)b * 2048 + qb * 64 + w * 16 + lg * 4 + i;
      int col = h * 128 + n * 16 + ll;
      aout[row * 1024 + col] = f2bf(o[n][i] * inv[i]);
    }
  }
}

// ---------------- launch ----------------

extern "C" void kernel_launch(void* const* d_in, const int* in_sizes, int n_in,
                              void* d_out, int out_size, void* d_ws, size_t ws_size,
                              hipStream_t stream) {
  const float* x     = (const float*)d_in[0];   // [8192, 1024]
  const float* wqkv  = (const float*)d_in[1];   // [3072, 1024]
  const float* wproj = (const float*)d_in[2];   // [1024, 1024]
  float* out = (float*)d_out;                   // [8192, 1024] fp32

  char* ws = (char*)d_ws;
  short* xb     = (short*)(ws);                          // 16,777,216 B
  short* wqkvb  = (short*)(ws + 16777216);               //  6,291,456 B
  short* wprojb = (short*)(ws + 23068672);               //  2,097,152 B
  short* qkvb   = (short*)(ws + 25165824);               // 50,331,648 B
  short* aoutb  = (short*)(ws + 75497472);               // 16,777,216 B (total ~92.3MB)

  cast_kernel<<<2048, 256, 0, stream>>>(x,     (unsigned short*)xb,     8388608 / 4);
  cast_kernel<<<768,  256, 0, stream>>>(wqkv,  (unsigned short*)wqkvb,  3145728 / 4);
  cast_kernel<<<256,  256, 0, stream>>>(wproj, (unsigned short*)wprojb, 1048576 / 4);

  gemm_bt<true><<<64 * 24, 256, 0, stream>>>(xb, wqkvb, (void*)qkvb, 8192, 3072, 1024);

  attn_fwd<<<32 * 32, 256, 0, stream>>>(qkvb, (unsigned short*)aoutb);

  gemm_bt<false><<<64 * 8, 256, 0, stream>>>(aoutb, wprojb, (void*)out, 8192, 1024, 1024);
}

// Round 2
// 279.948 us; speedup vs baseline: 1.8928x; 1.8928x over previous
//
#include <hip/hip_runtime.h>
#include <hip/hip_bf16.h>
#include <stdint.h>

// ---------------- common types / helpers ----------------

typedef __bf16 bf16x8 __attribute__((ext_vector_type(8)));
typedef float  f32x4  __attribute__((ext_vector_type(4)));
typedef float  f32x16 __attribute__((ext_vector_type(16)));
typedef short  s16x8  __attribute__((ext_vector_type(8)));
typedef unsigned int u32x4 __attribute__((ext_vector_type(4)));

__device__ __forceinline__ f32x4 mfma_bf16(s16x8 a, s16x8 b, f32x4 c) {
  return __builtin_amdgcn_mfma_f32_16x16x32_bf16(
      __builtin_bit_cast(bf16x8, a), __builtin_bit_cast(bf16x8, b), c, 0, 0, 0);
}

__device__ __forceinline__ f32x16 mfma32(s16x8 a, s16x8 b, f32x16 c) {
  return __builtin_amdgcn_mfma_f32_32x32x16_bf16(
      __builtin_bit_cast(bf16x8, a), __builtin_bit_cast(bf16x8, b), c, 0, 0, 0);
}

__device__ __forceinline__ unsigned short f2bf(float f) {
  unsigned u = __float_as_uint(f);
  u = u + 0x7FFFu + ((u >> 16) & 1u);   // RNE
  return (unsigned short)(u >> 16);
}

__device__ __forceinline__ unsigned cvt_pk_bf16(float lo, float hi) {
  unsigned r;
  asm("v_cvt_pk_bf16_f32 %0, %1, %2" : "=v"(r) : "v"(lo), "v"(hi));
  return r;
}

__device__ __forceinline__ void load_lds16(const void* g, void* l) {
  __builtin_amdgcn_global_load_lds(
      (const __attribute__((address_space(1))) void*)g,
      (__attribute__((address_space(3))) void*)l, 16, 0, 0);
}

// ---------------- cast fp32 -> bf16 ----------------

__global__ void cast_kernel(const float* __restrict__ in,
                            unsigned short* __restrict__ out, int n4) {
  int i = blockIdx.x * blockDim.x + threadIdx.x;
  int stride = gridDim.x * blockDim.x;
  for (; i < n4; i += stride) {
    float4 v = reinterpret_cast<const float4*>(in)[i];
    ushort4 o;
    o.x = f2bf(v.x); o.y = f2bf(v.y); o.z = f2bf(v.z); o.w = f2bf(v.w);
    reinterpret_cast<ushort4*>(out)[i] = o;
  }
}

// ---------------- GEMM: C[M,N] = A[M,K] * B[N,K]^T (both bf16, K-major) ----------------

template <bool OUT_BF16>
__global__ __launch_bounds__(256)
void gemm_bt(const short* __restrict__ A, const short* __restrict__ Bw,
             void* __restrict__ Cp, int M, int N, int K) {
  __shared__ __align__(16) short lds_a[4096];
  __shared__ __align__(16) short lds_b[4096];

  const int nbn = N >> 7;
  const int mb  = blockIdx.x / nbn;
  const int nb  = blockIdx.x % nbn;
  const int tid = threadIdx.x;
  const int w   = tid >> 6, l = tid & 63;
  const int lg  = l >> 4, ll = l & 15;
  const int wm  = w >> 1, wn = w & 1;

  f32x4 acc[4][4];
#pragma unroll
  for (int i = 0; i < 4; ++i)
#pragma unroll
    for (int j = 0; j < 4; ++j) acc[i][j] = {0.f, 0.f, 0.f, 0.f};

  const int KT = K >> 5;
  for (int kt = 0; kt < KT; ++kt) {
#pragma unroll
    for (int cc = 0; cc < 4; ++cc) {
      int chunk = w * 4 + cc;
      int c8    = chunk & 7;
      int row   = c8 * 16 + (l >> 2);
      int sg    = (l & 3) ^ (row & 3);
      if (chunk < 8) {
        const short* src = A + (size_t)(mb * 128 + row) * K + kt * 32 + sg * 8;
        load_lds16(src, lds_a + c8 * 512);
      } else {
        const short* src = Bw + (size_t)(nb * 128 + row) * K + kt * 32 + sg * 8;
        load_lds16(src, lds_b + c8 * 512);
      }
    }
    __syncthreads();

    s16x8 af[4], bf[4];
#pragma unroll
    for (int mi = 0; mi < 4; ++mi) {
      int row  = wm * 64 + mi * 16 + ll;
      int slot = lg ^ (row & 3);
      af[mi] = *reinterpret_cast<const s16x8*>(lds_a + row * 32 + slot * 8);
    }
#pragma unroll
    for (int nj = 0; nj < 4; ++nj) {
      int row  = wn * 64 + nj * 16 + ll;
      int slot = lg ^ (row & 3);
      bf[nj] = *reinterpret_cast<const s16x8*>(lds_b + row * 32 + slot * 8);
    }
#pragma unroll
    for (int mi = 0; mi < 4; ++mi)
#pragma unroll
      for (int nj = 0; nj < 4; ++nj)
        acc[mi][nj] = mfma_bf16(af[mi], bf[nj], acc[mi][nj]);
    __syncthreads();
  }

#pragma unroll
  for (int mi = 0; mi < 4; ++mi) {
#pragma unroll
    for (int i = 0; i < 4; ++i) {
      size_t row = (size_t)(mb * 128 + wm * 64 + mi * 16 + lg * 4 + i);
#pragma unroll
      for (int nj = 0; nj < 4; ++nj) {
        int col = nb * 128 + wn * 64 + nj * 16 + ll;
        if (OUT_BF16)
          ((unsigned short*)Cp)[row * N + col] = f2bf(acc[mi][nj][i]);
        else
          ((float*)Cp)[row * N + col] = acc[mi][nj][i];
      }
    }
  }
}

// ---------------- flash attention v2: 8-wave, 32x32 MFMA, swapped QK^T ----------------
// grid = 32 (b,h) * 8 q-blocks of 256 rows; 512 threads = 8 waves, each wave
// owns 32 q rows. KVBLK=64, K/V double-buffered in LDS.
// Swapped QK^T: st = mfma(A=K, B=Q) -> S^T, col(lane&31)=qrow, so softmax is
// lane-local over 32 regs + one shfl_xor(32) partner combine. P goes back to
// the PV A-operand in-register via cvt_pk_bf16 + shfl_xor word exchange.

__global__ __launch_bounds__(512, 2)
void attn_fwd(const short* __restrict__ qkv, unsigned short* __restrict__ aout) {
  __shared__ __align__(16) short k_lds[2][64 * 128];   // [buf][krow][d] swizzled (32KB)
  __shared__ __align__(16) short v_lds[2][128 * 64];   // [buf][d][krow] swizzled (32KB)

  const int bh = blockIdx.x >> 3;
  const int qb = blockIdx.x & 7;
  const int b = bh >> 3, h = bh & 7;
  const int tid = threadIdx.x;
  const int w = tid >> 6, l = tid & 63;
  const int col = l & 31, hi = l >> 5;

  const size_t base = (size_t)b * 2048 * 3072 + (size_t)h * 128;
  const int qrow0 = qb * 256 + w * 32;

  // Q fragments (B-operand): lane holds Q[qrow=col][d = ks*16 + hi*8 .. +8]
  s16x8 qf[8];
  {
    const short* qp = qkv + base + (size_t)(qrow0 + col) * 3072 + hi * 8;
#pragma unroll
    for (int ks = 0; ks < 8; ++ks)
      qf[ks] = *reinterpret_cast<const s16x8*>(qp + ks * 16);
  }

  f32x16 oacc[4];
#pragma unroll
  for (int nt = 0; nt < 4; ++nt)
#pragma unroll
    for (int r = 0; r < 16; ++r) oacc[nt][r] = 0.f;
  float M = -1e30f, L = 0.f;
  const float csc = 0.08838834764831845f * 1.4426950408889634f;  // scale*log2e

  // V staging regs (waves 0..3 / tid<256): rows vr_r0, vr_r0+1, cols vr_c0..+15
  s16x8 vr0a, vr0b, vr1a, vr1b;
  const int vr_r0 = (tid & 31) * 2;
  const int vr_c0 = ((tid >> 5) & 7) * 16;

  auto stage_k = [&](int kb, int bf) {
    int wk = w - 4;
#pragma unroll
    for (int cc = 0; cc < 4; ++cc) {
      int c = wk * 4 + cc;
      int row = c * 4 + (l >> 4);
      int sd = (l & 15) ^ (row & 7);
      load_lds16(qkv + base + 1024 + (size_t)(kb * 64 + row) * 3072 + sd * 8,
                 &k_lds[bf][c * 512]);
    }
  };
  auto load_v = [&](int kb) {
    const short* g = qkv + base + 2048 + (size_t)(kb * 64 + vr_r0) * 3072 + vr_c0;
    vr0a = *reinterpret_cast<const s16x8*>(g);
    vr0b = *reinterpret_cast<const s16x8*>(g + 8);
    vr1a = *reinterpret_cast<const s16x8*>(g + 3072);
    vr1b = *reinterpret_cast<const s16x8*>(g + 3072 + 8);
  };
  auto write_v = [&](int bf) {
    char* vbase = reinterpret_cast<char*>(v_lds[bf]);
#pragma unroll
    for (int j = 0; j < 16; ++j) {
      int d = vr_c0 + j;
      unsigned e0 = (unsigned short)(j < 8 ? vr0a[j] : vr0b[j - 8]);
      unsigned e1 = (unsigned short)(j < 8 ? vr1a[j] : vr1b[j - 8]);
      int byte = d * 128 + ((((vr_r0 * 2) >> 4) ^ (d & 7)) << 4) + ((vr_r0 * 2) & 15);
      *reinterpret_cast<unsigned*>(vbase + byte) = e0 | (e1 << 16);
    }
  };

  // prologue: stage tile 0 into buf 0
  if (w >= 4) stage_k(0, 0);
  else { load_v(0); write_v(0); }
  __syncthreads();

  for (int kb = 0; kb < 32; ++kb) {
    const int bf = kb & 1;
    if (kb < 31) {
      if (w >= 4) stage_k(kb + 1, bf ^ 1);
      else load_v(kb + 1);
    }

    // ---- S^T = K Q^T over the 64-row K tile
    f32x16 st[2];
#pragma unroll
    for (int kt = 0; kt < 2; ++kt)
#pragma unroll
      for (int r = 0; r < 16; ++r) st[kt][r] = 0.f;
    const char* kbase = reinterpret_cast<const char*>(k_lds[bf]);
#pragma unroll
    for (int ks = 0; ks < 8; ++ks) {
#pragma unroll
      for (int kt = 0; kt < 2; ++kt) {
        int krow = kt * 32 + col;
        int slot = (ks * 2 + hi) ^ (krow & 7);
        s16x8 ak = *reinterpret_cast<const s16x8*>(kbase + krow * 256 + slot * 16);
        st[kt] = mfma32(ak, qf[ks], st[kt]);
      }
    }

    // ---- online softmax (lane owns q-row = col; partner = lane^32)
    float pm = st[0][0];
#pragma unroll
    for (int r = 1; r < 16; ++r) pm = fmaxf(pm, st[0][r]);
#pragma unroll
    for (int r = 0; r < 16; ++r) pm = fmaxf(pm, st[1][r]);
    pm *= csc;
    pm = fmaxf(pm, __shfl_xor(pm, 32));
    if (!__all(pm <= M + 8.0f)) {     // defer-max, THR=8 (exp2 domain)
      float Mn = fmaxf(M, pm);
      float f = exp2f(M - Mn);
      M = Mn; L *= f;
#pragma unroll
      for (int r = 0; r < 16; ++r) {
        float fr = __shfl(f, (r & 3) + 8 * (r >> 2) + 4 * hi);
#pragma unroll
        for (int nt = 0; nt < 4; ++nt) oacc[nt][r] *= fr;
      }
    }
    float rs = 0.f;
#pragma unroll
    for (int kt = 0; kt < 2; ++kt)
#pragma unroll
      for (int r = 0; r < 16; ++r) {
        float e = exp2f(fmaf(st[kt][r], csc, -M));
        st[kt][r] = e;
        rs += e;
      }
    rs += __shfl_xor(rs, 32);
    L += rs;

    // ---- P -> bf16 A-operand frags, in-register
    unsigned wd[16], pw[16];
#pragma unroll
    for (int i = 0; i < 8; ++i) {
      wd[i]     = cvt_pk_bf16(st[0][2 * i], st[0][2 * i + 1]);
      wd[8 + i] = cvt_pk_bf16(st[1][2 * i], st[1][2 * i + 1]);
    }
#pragma unroll
    for (int i = 0; i < 16; ++i) pw[i] = __shfl_xor(wd[i], 32);
    s16x8 pa[4];
#pragma unroll
    for (int kt = 0; kt < 2; ++kt) {
      int bq = kt * 8;
      u32x4 f0 = {hi ? pw[bq + 2] : wd[bq + 0], hi ? pw[bq + 3] : wd[bq + 1],
                  hi ? wd[bq + 2] : pw[bq + 0], hi ? wd[bq + 3] : pw[bq + 1]};
      u32x4 f1 = {hi ? pw[bq + 6] : wd[bq + 4], hi ? pw[bq + 7] : wd[bq + 5],
                  hi ? wd[bq + 6] : pw[bq + 4], hi ? wd[bq + 7] : pw[bq + 5]};
      pa[kt * 2 + 0] = __builtin_bit_cast(s16x8, f0);
      pa[kt * 2 + 1] = __builtin_bit_cast(s16x8, f1);
    }

    // ---- O += P V
    const char* vbase = reinterpret_cast<const char*>(v_lds[bf]);
#pragma unroll
    for (int ks = 0; ks < 4; ++ks) {
#pragma unroll
      for (int nt = 0; nt < 4; ++nt) {
        int d = nt * 32 + col;
        int slot = (ks * 2 + hi) ^ (d & 7);
        s16x8 bv = *reinterpret_cast<const s16x8*>(vbase + d * 128 + slot * 16);
        oacc[nt] = mfma32(pa[ks], bv, oacc[nt]);
      }
    }

    if (kb < 31 && w < 4) write_v(bf ^ 1);
    __syncthreads();
  }

  // ---- epilogue: normalize, store bf16 [B*N, 1024]
  float invl = 1.f / L;
#pragma unroll
  for (int r = 0; r < 16; ++r) {
    int qr = (r & 3) + 8 * (r >> 2) + 4 * hi;
    float il = __shfl(invl, qr);
    size_t row = (size_t)b * 2048 + qrow0 + qr;
#pragma unroll
    for (int nt = 0; nt < 4; ++nt)
      aout[row * 1024 + h * 128 + nt * 32 + col] = f2bf(oacc[nt][r] * il);
  }
}

// ---------------- launch ----------------

extern "C" void kernel_launch(void* const* d_in, const int* in_sizes, int n_in,
                              void* d_out, int out_size, void* d_ws, size_t ws_size,
                              hipStream_t stream) {
  const float* x     = (const float*)d_in[0];   // [8192, 1024]
  const float* wqkv  = (const float*)d_in[1];   // [3072, 1024]
  const float* wproj = (const float*)d_in[2];   // [1024, 1024]
  float* out = (float*)d_out;                   // [8192, 1024] fp32

  char* ws = (char*)d_ws;
  short* xb     = (short*)(ws);                          // 16,777,216 B
  short* wqkvb  = (short*)(ws + 16777216);               //  6,291,456 B
  short* wprojb = (short*)(ws + 23068672);               //  2,097,152 B
  short* qkvb   = (short*)(ws + 25165824);               // 50,331,648 B
  short* aoutb  = (short*)(ws + 75497472);               // 16,777,216 B (total ~92.3MB)

  cast_kernel<<<2048, 256, 0, stream>>>(x,     (unsigned short*)xb,     8388608 / 4);
  cast_kernel<<<768,  256, 0, stream>>>(wqkv,  (unsigned short*)wqkvb,  3145728 / 4);
  cast_kernel<<<256,  256, 0, stream>>>(wproj, (unsigned short*)wprojb, 1048576 / 4);

  gemm_bt<true><<<64 * 24, 256, 0, stream>>>(xb, wqkvb, (void*)qkvb, 8192, 3072, 1024);

  attn_fwd<<<32 * 8, 512, 0, stream>>>(qkvb, (unsigned short*)aoutb);

  gemm_bt<false><<<64 * 8, 256, 0, stream>>>(aoutb, wprojb, (void*)out, 8192, 1024, 1024);
}